// Round 1
// baseline (916.384 us; speedup 1.0000x reference)
//
#include <hip/hip_runtime.h>

#define FLTMAX 3.402823466e+38f

// ---------------------------------------------------------------------------
// Geometry:
//   Layer1: B=1024, N=784, Np=896, S=7, F=512, I=8, K=4
//   Layer2: B=1024, N=512, Np=512, S=4, F=10,  I=8, K=4
// P1 plane (s,i,k): [1024 x 512]; P2 plane: [1024 x 10]
// ---------------------------------------------------------------------------

__global__ void init_kernel(float* __restrict__ acc1, unsigned* __restrict__ stats1)
{
    int gid = blockIdx.x * 256 + threadIdx.x;
    if (gid < 1024 * 512) acc1[gid] = 0.f;
    if (gid < 224) { stats1[gid * 2] = 0x7F7FFFFFu; stats1[gid * 2 + 1] = 0u; }
}

// xq1[b][n] = rint(clip(x,0,1)*255), padded to 896 with 0; sx1[b] = row sum
__global__ void prep1_kernel(const float* __restrict__ x, float* __restrict__ xq1,
                             float* __restrict__ sx1)
{
    __shared__ float red[128];
    int b = blockIdx.x;
    float psum = 0.f;
    for (int n = threadIdx.x; n < 896; n += 128) {
        float v = 0.f;
        if (n < 784) {
            float xv = x[b * 784 + n];
            xv = fminf(fmaxf(xv, 0.f), 1.f);
            v = rintf(__fmul_rn(xv, 255.f));
        }
        xq1[b * 896 + n] = v;
        psum += v;  // integer-valued, exact in any order
    }
    red[threadIdx.x] = psum;
    __syncthreads();
    for (int w = 64; w >= 1; w >>= 1) {
        if (threadIdx.x < w) red[threadIdx.x] += red[threadIdx.x + w];
        __syncthreads();
    }
    if (threadIdx.x == 0) sx1[b] = red[0];
}

// g1[k][f][n] = (slc*0.9+0.3)*(1+0.05*noise), n padded to 896 with 0
__global__ void prepg1_kernel(const float* __restrict__ w1, const float* __restrict__ noise1,
                              float* __restrict__ g1)
{
    int gid = blockIdx.x * 256 + threadIdx.x;
    if (gid >= 512 * 896) return;
    int f = gid / 896, n = gid % 896;
    float gv[4] = {0.f, 0.f, 0.f, 0.f};
    if (n < 784) {
        float w = w1[f * 784 + n];
        float Xi = fminf(fmaxf(rintf(__fmul_rn(__fmul_rn(__fadd_rn(w, 1.f), 0.5f), 255.f)),
                               0.f), 255.f);
        int xi = (int)Xi;
#pragma unroll
        for (int k = 0; k < 4; ++k) {
            int slc = (xi >> (2 * k)) & 3;
            float base = __fadd_rn(__fmul_rn((float)slc, 0.9f), 0.3f);
            float nf = __fadd_rn(1.f, __fmul_rn(0.05f, noise1[(f * 896 + n) * 4 + k]));
            gv[k] = __fmul_rn(base, nf);
        }
    }
#pragma unroll
    for (int k = 0; k < 4; ++k) g1[(k * 512 + f) * 896 + n] = gv[k];
}

// g2t[n][k][f] layout for layer-2 matmul
__global__ void prepg2_kernel(const float* __restrict__ w3, const float* __restrict__ noise3,
                              float* __restrict__ g2t)
{
    int gid = blockIdx.x * 256 + threadIdx.x;
    if (gid >= 10 * 512) return;
    int f = gid / 512, n = gid % 512;
    float w = w3[f * 512 + n];
    float Xi = fminf(fmaxf(rintf(__fmul_rn(__fmul_rn(__fadd_rn(w, 1.f), 0.5f), 255.f)),
                           0.f), 255.f);
    int xi = (int)Xi;
#pragma unroll
    for (int k = 0; k < 4; ++k) {
        int slc = (xi >> (2 * k)) & 3;
        float base = __fadd_rn(__fmul_rn((float)slc, 0.9f), 0.3f);
        float nf = __fadd_rn(1.f, __fmul_rn(0.05f, noise3[(f * 512 + n) * 4 + k]));
        g2t[n * 40 + k * 10 + f] = __fmul_rn(base, nf);
    }
}

// Dummy-column path: one workgroup per (i,s) plane; Dq[(i*S+s)*1024 + b]
__global__ void dq_kernel(const float* __restrict__ xq, float* __restrict__ Dq,
                          int S, int rowstride)
{
    __shared__ float red[512];
    const int i = blockIdx.x / S, s = blockIdx.x % S;
    const int tid = threadIdx.x;
    float D[4];
    float mn = FLTMAX, mx = -FLTMAX;
#pragma unroll
    for (int u = 0; u < 4; ++u) {
        int b = tid + u * 256;
        const float4* row = (const float4*)&xq[b * rowstride + s * 128];
        int c = 0;
#pragma unroll 8
        for (int q = 0; q < 32; ++q) {
            float4 v = row[q];
            c += (((int)v.x >> i) & 1) + (((int)v.y >> i) & 1) +
                 (((int)v.z >> i) & 1) + (((int)v.w >> i) & 1);
        }
        D[u] = __fmul_rn((float)c, 0.3f);
        mn = fminf(mn, D[u]);
        mx = fmaxf(mx, D[u]);
    }
    red[tid] = mn; red[256 + tid] = mx;
    __syncthreads();
    for (int w = 128; w >= 1; w >>= 1) {
        if (tid < w) {
            red[tid] = fminf(red[tid], red[tid + w]);
            red[256 + tid] = fmaxf(red[256 + tid], red[256 + tid + w]);
        }
        __syncthreads();
    }
    mn = red[0]; mx = red[256];
    float step = __fmul_rn(__fsub_rn(mx, mn), 0.03125f);
    if (step <= 0.f) step = 1.f;
#pragma unroll
    for (int u = 0; u < 4; ++u) {
        int b = tid + u * 256;
        float idx = fminf(fmaxf(floorf(__fdiv_rn(__fsub_rn(D[u], mn), step)), 0.f), 31.f);
        Dq[(i * S + s) * 1024 + b] = __fadd_rn(__fmul_rn(idx, step), mn);
    }
}

// dterm[b] = sum_{i,s} Dq[i,s,b] * (85 * 2^i)   (sum_k scal[i,k] = 85*2^i)
__global__ void dterm_kernel(const float* __restrict__ Dq, float* __restrict__ dterm, int S)
{
    int b = blockIdx.x * 256 + threadIdx.x;
    if (b >= 1024) return;
    float sum = 0.f;
    for (int i = 0; i < 8; ++i) {
        float sc = (float)(85 << i);
        for (int s = 0; s < S; ++s) sum = fmaf(Dq[(i * S + s) * 1024 + b], sc, sum);
    }
    dterm[b] = sum;
}

// Layer-1 GEMM: P[row][col] = sum_a bit_i(xq[b][s*128+a]) * g1[k][f][s*128+a]
// rows = (i-i0)*1024 + b (chunk-local), cols = k*512 + f.  64x64 tile, 256 thr.
__global__ __launch_bounds__(256) void mm1_kernel(
    const float* __restrict__ xq, const float* __restrict__ g1,
    float* __restrict__ P, unsigned* __restrict__ stats, int s, int i0)
{
    __shared__ __align__(16) float As[128 * 68];  // A^T[a][r], stride 68
    __shared__ __align__(16) float Bs[128 * 68];  // B[a][c],  stride 68
    __shared__ float red[512];
    const int tid = threadIdx.x;
    const int rowChunk = blockIdx.x * 64;       // [0, ni*1024)
    const int i = i0 + (rowChunk >> 10);
    const int b0 = rowChunk & 1023;
    const int colBase = blockIdx.y * 64;        // [0, 2048)
    const int k = colBase >> 9;
    const int f0 = colBase & 511;
    const int nbase = s * 128;

    for (int t = tid; t < 64 * 128; t += 256) {
        int a = t & 127, r = t >> 7;
        float xv = xq[(b0 + r) * 896 + nbase + a];
        As[a * 68 + r] = (float)((((int)xv) >> i) & 1);
        Bs[a * 68 + r] = g1[((k << 9) + f0 + r) * 896 + nbase + a];
    }
    __syncthreads();

    const int tx = tid & 15, ty = tid >> 4;
    float acc[4][4] = {};
#pragma unroll 4
    for (int a = 0; a < 128; ++a) {
        float4 av = *(const float4*)&As[a * 68 + (ty << 2)];
        float4 bv = *(const float4*)&Bs[a * 68 + (tx << 2)];
        float ar[4] = {av.x, av.y, av.z, av.w};
        float br[4] = {bv.x, bv.y, bv.z, bv.w};
#pragma unroll
        for (int u = 0; u < 4; ++u)
#pragma unroll
            for (int v = 0; v < 4; ++v) acc[u][v] = fmaf(ar[u], br[v], acc[u][v]);
    }

#pragma unroll
    for (int u = 0; u < 4; ++u) {
        int row = rowChunk + (ty << 2) + u;
        float4 v = make_float4(acc[u][0], acc[u][1], acc[u][2], acc[u][3]);
        *(float4*)&P[(size_t)row * 2048 + colBase + (tx << 2)] = v;
    }

    float mn = acc[0][0], mx = acc[0][0];
#pragma unroll
    for (int u = 0; u < 4; ++u)
#pragma unroll
        for (int v = 0; v < 4; ++v) { mn = fminf(mn, acc[u][v]); mx = fmaxf(mx, acc[u][v]); }
    red[tid] = mn; red[256 + tid] = mx;
    __syncthreads();
    for (int w = 128; w >= 1; w >>= 1) {
        if (tid < w) {
            red[tid] = fminf(red[tid], red[tid + w]);
            red[256 + tid] = fmaxf(red[256 + tid], red[256 + tid + w]);
        }
        __syncthreads();
    }
    if (tid == 0) {
        int slot = ((s * 8 + i) * 4 + k) * 2;
        atomicMin(&stats[slot], __float_as_uint(red[0]));      // P >= 0: uint order == float order
        atomicMax(&stats[slot + 1], __float_as_uint(red[256]));
    }
}

// ADC-quantize chunk planes and accumulate sum_{i,k} Pq*scal into acc1[b][f]
__global__ void quant1_kernel(const float* __restrict__ P, const unsigned* __restrict__ stats,
                              float* __restrict__ acc1, int s, int i0, int ni)
{
    int gid = blockIdx.x * 256 + threadIdx.x;  // 524288
    int b = gid >> 9, f = gid & 511;
    float sum = 0.f;
    for (int il = 0; il < ni; ++il) {
        int i = i0 + il;
#pragma unroll
        for (int k = 0; k < 4; ++k) {
            int slot = ((s * 8 + i) * 4 + k) * 2;
            float mn = __uint_as_float(stats[slot]);
            float mx = __uint_as_float(stats[slot + 1]);
            float step = __fmul_rn(__fsub_rn(mx, mn), 0.03125f);
            if (step <= 0.f) step = 1.f;
            float val = P[(size_t)(il * 1024 + b) * 2048 + (k << 9) + f];
            float idx = fminf(fmaxf(floorf(__fdiv_rn(__fsub_rn(val, mn), step)), 0.f), 31.f);
            float pq = __fadd_rn(__fmul_rn(idx, step), mn);
            sum = fmaf(pq, (float)(1 << (i + 2 * k)), sum);
        }
    }
    acc1[gid] += sum;
}

// out1 -> tanh -> xq2 (layer-2 quantized input codes)
__global__ void finish1_kernel(const float* __restrict__ acc1, const float* __restrict__ dterm1,
                               const float* __restrict__ sx1, float* __restrict__ xq2)
{
    int gid = blockIdx.x * 256 + threadIdx.x;  // 524288
    int b = gid >> 9;
    float total = __fsub_rn(acc1[gid], dterm1[b]);
    float acc = __fdiv_rn(total, 0.9f);
    float o = __fsub_rn(__fdiv_rn(__fmul_rn(2.f, acc), 65025.f), __fdiv_rn(sx1[b], 255.f));
    float h = tanhf(o);
    h = fminf(fmaxf(h, 0.f), 1.f);
    xq2[gid] = rintf(__fmul_rn(h, 255.f));
}

__global__ void sx2_kernel(const float* __restrict__ xq2, float* __restrict__ sx2)
{
    __shared__ float red[128];
    int b = blockIdx.x;
    float psum = 0.f;
    for (int n = threadIdx.x; n < 512; n += 128) psum += xq2[b * 512 + n];
    red[threadIdx.x] = psum;
    __syncthreads();
    for (int w = 64; w >= 1; w >>= 1) {
        if (threadIdx.x < w) red[threadIdx.x] += red[threadIdx.x + w];
        __syncthreads();
    }
    if (threadIdx.x == 0) sx2[b] = red[0];
}

// Layer-2 matmul: thread per (s,b,f), 32 accumulators (i,k)
__global__ void mm2_kernel(const float* __restrict__ xq2, const float* __restrict__ g2t,
                           float* __restrict__ P2)
{
    int gid = blockIdx.x * 256 + threadIdx.x;  // 40960
    if (gid >= 40960) return;
    int f = gid % 10;
    int b = (gid / 10) & 1023;
    int s = gid / 10240;
    float acc[8][4] = {};
    for (int a = 0; a < 128; ++a) {
        int n = s * 128 + a;
        int xi = (int)xq2[b * 512 + n];
        float g0 = g2t[n * 40 + f];
        float gA = g2t[n * 40 + 10 + f];
        float gB = g2t[n * 40 + 20 + f];
        float gC = g2t[n * 40 + 30 + f];
#pragma unroll
        for (int i = 0; i < 8; ++i) {
            float bi = (float)((xi >> i) & 1);
            acc[i][0] = fmaf(bi, g0, acc[i][0]);
            acc[i][1] = fmaf(bi, gA, acc[i][1]);
            acc[i][2] = fmaf(bi, gB, acc[i][2]);
            acc[i][3] = fmaf(bi, gC, acc[i][3]);
        }
    }
#pragma unroll
    for (int i = 0; i < 8; ++i)
#pragma unroll
        for (int k = 0; k < 4; ++k)
            P2[(size_t)((s * 8 + i) * 4 + k) * 10240 + b * 10 + f] = acc[i][k];
}

__global__ void stat2_kernel(const float* __restrict__ P2, float2* __restrict__ stats2)
{
    __shared__ float red[512];
    int p = blockIdx.x;  // 128 planes
    int tid = threadIdx.x;
    float mn = FLTMAX, mx = -FLTMAX;
    for (int t = tid; t < 10240; t += 256) {
        float v = P2[(size_t)p * 10240 + t];
        mn = fminf(mn, v); mx = fmaxf(mx, v);
    }
    red[tid] = mn; red[256 + tid] = mx;
    __syncthreads();
    for (int w = 128; w >= 1; w >>= 1) {
        if (tid < w) {
            red[tid] = fminf(red[tid], red[tid + w]);
            red[256 + tid] = fmaxf(red[256 + tid], red[256 + tid + w]);
        }
        __syncthreads();
    }
    if (tid == 0) {
        float step = __fmul_rn(__fsub_rn(red[256], red[0]), 0.03125f);
        if (step <= 0.f) step = 1.f;
        stats2[p] = make_float2(red[0], step);
    }
}

__global__ void out2_kernel(const float* __restrict__ P2, const float2* __restrict__ stats2,
                            const float* __restrict__ dterm2, const float* __restrict__ sx2,
                            float* __restrict__ out)
{
    int gid = blockIdx.x * 256 + threadIdx.x;  // 10240
    if (gid >= 10240) return;
    int b = gid / 10;
    float sum = 0.f;
    for (int s = 0; s < 4; ++s)
        for (int i = 0; i < 8; ++i)
#pragma unroll
            for (int k = 0; k < 4; ++k) {
                int p = (s * 8 + i) * 4 + k;
                float2 st = stats2[p];
                float val = P2[(size_t)p * 10240 + gid];
                float idx = fminf(fmaxf(floorf(__fdiv_rn(__fsub_rn(val, st.x), st.y)), 0.f), 31.f);
                float pq = __fadd_rn(__fmul_rn(idx, st.y), st.x);
                sum = fmaf(pq, (float)(1 << (i + 2 * k)), sum);
            }
    float total = __fsub_rn(sum, dterm2[b]);
    float acc = __fdiv_rn(total, 0.9f);
    out[gid] = __fsub_rn(__fdiv_rn(__fmul_rn(2.f, acc), 65025.f), __fdiv_rn(sx2[b], 255.f));
}

extern "C" void kernel_launch(void* const* d_in, const int* in_sizes, int n_in,
                              void* d_out, int out_size, void* d_ws, size_t ws_size,
                              hipStream_t stream)
{
    const float* x      = (const float*)d_in[0];
    const float* w1     = (const float*)d_in[1];
    const float* w3     = (const float*)d_in[2];
    const float* noise1 = (const float*)d_in[3];
    const float* noise3 = (const float*)d_in[4];
    float* out = (float*)d_out;
    float* ws  = (float*)d_ws;

    // ws layout (float offsets, 16-float aligned)
    float*    xq1    = ws + 0;         // 1024*896
    float*    g1     = ws + 917504;    // 4*512*896
    float*    acc1   = ws + 2752512;   // 1024*512
    float*    xq2    = ws + 3276800;   // 1024*512
    float*    P2     = ws + 3801088;   // 128*10240
    float*    g2t    = ws + 5111808;   // 512*40
    float*    Dq1    = ws + 5132288;   // 56*1024
    float*    Dq2    = ws + 5189632;   // 32*1024
    float*    sx1    = ws + 5222400;   // 1024
    float*    sx2    = ws + 5223424;   // 1024
    float*    dterm1 = ws + 5224448;   // 1024
    float*    dterm2 = ws + 5225472;   // 1024
    float2*   stats2 = (float2*)(ws + 5226496);   // 128 pairs
    unsigned* stats1 = (unsigned*)(ws + 5226752); // 224*2
    float*    Ps     = ws + 5227200;   // ni * 1024 * 2048

    const size_t fixedf = 5227200;
    int ni = 8;  // i-planes per P chunk; shrink to fit ws
    while (ni > 1 && (fixedf + (size_t)ni * 2097152) * sizeof(float) > ws_size) ni >>= 1;

    init_kernel<<<2048, 256, 0, stream>>>(acc1, stats1);
    prep1_kernel<<<1024, 128, 0, stream>>>(x, xq1, sx1);
    prepg1_kernel<<<1792, 256, 0, stream>>>(w1, noise1, g1);
    dq_kernel<<<56, 256, 0, stream>>>(xq1, Dq1, 7, 896);
    dterm_kernel<<<4, 256, 0, stream>>>(Dq1, dterm1, 7);

    for (int s = 0; s < 7; ++s)
        for (int i0 = 0; i0 < 8; i0 += ni) {
            mm1_kernel<<<dim3(16 * ni, 32), 256, 0, stream>>>(xq1, g1, Ps, stats1, s, i0);
            quant1_kernel<<<2048, 256, 0, stream>>>(Ps, stats1, acc1, s, i0, ni);
        }

    finish1_kernel<<<2048, 256, 0, stream>>>(acc1, dterm1, sx1, xq2);
    sx2_kernel<<<1024, 128, 0, stream>>>(xq2, sx2);
    prepg2_kernel<<<20, 256, 0, stream>>>(w3, noise3, g2t);
    dq_kernel<<<32, 256, 0, stream>>>(xq2, Dq2, 4, 512);
    dterm_kernel<<<4, 256, 0, stream>>>(Dq2, dterm2, 4);
    mm2_kernel<<<160, 256, 0, stream>>>(xq2, g2t, P2);
    stat2_kernel<<<128, 256, 0, stream>>>(P2, stats2);
    out2_kernel<<<40, 256, 0, stream>>>(P2, stats2, dterm2, sx2, out);
}

// Round 2
// 683.631 us; speedup vs baseline: 1.3405x; 1.3405x over previous
//
#include <hip/hip_runtime.h>

#define FLTMAX 3.402823466e+38f

// ---------------------------------------------------------------------------
// Geometry:
//   Layer1: B=1024, N=784, Np=896, S=7, F=512, I=8, K=4
//   Layer2: B=1024, N=512, Np=512, S=4, F=10,  I=8, K=4
// P1 plane (s,i,k): [1024 x 512]; P2 plane: [1024 x 10]
// ---------------------------------------------------------------------------

__global__ void init_kernel(float* __restrict__ acc1, unsigned* __restrict__ stats1)
{
    int gid = blockIdx.x * 256 + threadIdx.x;
    if (gid < 1024 * 512) acc1[gid] = 0.f;
    if (gid < 224) { stats1[gid * 2] = 0x7F7FFFFFu; stats1[gid * 2 + 1] = 0u; }
}

// xq1[b][n] = rint(clip(x,0,1)*255), padded to 896 with 0; sx1[b] = row sum
__global__ void prep1_kernel(const float* __restrict__ x, float* __restrict__ xq1,
                             float* __restrict__ sx1)
{
    __shared__ float red[128];
    int b = blockIdx.x;
    float psum = 0.f;
    for (int n = threadIdx.x; n < 896; n += 128) {
        float v = 0.f;
        if (n < 784) {
            float xv = x[b * 784 + n];
            xv = fminf(fmaxf(xv, 0.f), 1.f);
            v = rintf(__fmul_rn(xv, 255.f));
        }
        xq1[b * 896 + n] = v;
        psum += v;  // integer-valued, exact in any order
    }
    red[threadIdx.x] = psum;
    __syncthreads();
    for (int w = 64; w >= 1; w >>= 1) {
        if (threadIdx.x < w) red[threadIdx.x] += red[threadIdx.x + w];
        __syncthreads();
    }
    if (threadIdx.x == 0) sx1[b] = red[0];
}

// g1[k*512+f][n] = (slc*0.9+0.3)*(1+0.05*noise), n padded to 896 with 0
__global__ void prepg1_kernel(const float* __restrict__ w1, const float* __restrict__ noise1,
                              float* __restrict__ g1)
{
    int gid = blockIdx.x * 256 + threadIdx.x;
    if (gid >= 512 * 896) return;
    int f = gid / 896, n = gid % 896;
    float gv[4] = {0.f, 0.f, 0.f, 0.f};
    if (n < 784) {
        float w = w1[f * 784 + n];
        float Xi = fminf(fmaxf(rintf(__fmul_rn(__fmul_rn(__fadd_rn(w, 1.f), 0.5f), 255.f)),
                               0.f), 255.f);
        int xi = (int)Xi;
#pragma unroll
        for (int k = 0; k < 4; ++k) {
            int slc = (xi >> (2 * k)) & 3;
            float base = __fadd_rn(__fmul_rn((float)slc, 0.9f), 0.3f);
            float nf = __fadd_rn(1.f, __fmul_rn(0.05f, noise1[(f * 896 + n) * 4 + k]));
            gv[k] = __fmul_rn(base, nf);
        }
    }
#pragma unroll
    for (int k = 0; k < 4; ++k) g1[(k * 512 + f) * 896 + n] = gv[k];
}

// generic tiled transpose: out[c][r] = in[r][c]; R, C multiples of 32
__global__ void transpose_kernel(const float* __restrict__ in, float* __restrict__ out,
                                 int R, int C)
{
    __shared__ float tile[32][33];
    int c0 = blockIdx.x * 32, r0 = blockIdx.y * 32;
    int tx = threadIdx.x & 31, ty4 = (threadIdx.x >> 5) * 4;
#pragma unroll
    for (int u = 0; u < 4; ++u)
        tile[ty4 + u][tx] = in[(r0 + ty4 + u) * C + c0 + tx];
    __syncthreads();
#pragma unroll
    for (int u = 0; u < 4; ++u)
        out[(c0 + ty4 + u) * R + r0 + tx] = tile[tx][ty4 + u];
}

// g2t[n][k][f] layout for layer-2 matmul
__global__ void prepg2_kernel(const float* __restrict__ w3, const float* __restrict__ noise3,
                              float* __restrict__ g2t)
{
    int gid = blockIdx.x * 256 + threadIdx.x;
    if (gid >= 10 * 512) return;
    int f = gid / 512, n = gid % 512;
    float w = w3[f * 512 + n];
    float Xi = fminf(fmaxf(rintf(__fmul_rn(__fmul_rn(__fadd_rn(w, 1.f), 0.5f), 255.f)),
                           0.f), 255.f);
    int xi = (int)Xi;
#pragma unroll
    for (int k = 0; k < 4; ++k) {
        int slc = (xi >> (2 * k)) & 3;
        float base = __fadd_rn(__fmul_rn((float)slc, 0.9f), 0.3f);
        float nf = __fadd_rn(1.f, __fmul_rn(0.05f, noise3[(f * 512 + n) * 4 + k]));
        g2t[n * 40 + k * 10 + f] = __fmul_rn(base, nf);
    }
}

// Dummy-column path: one workgroup per (i,s) plane; Dq[(i*S+s)*1024 + b]
__global__ void dq_kernel(const float* __restrict__ xq, float* __restrict__ Dq,
                          int S, int rowstride)
{
    __shared__ float red[512];
    const int i = blockIdx.x / S, s = blockIdx.x % S;
    const int tid = threadIdx.x;
    float D[4];
    float mn = FLTMAX, mx = -FLTMAX;
#pragma unroll
    for (int u = 0; u < 4; ++u) {
        int b = tid + u * 256;
        const float4* row = (const float4*)&xq[b * rowstride + s * 128];
        int c = 0;
#pragma unroll 8
        for (int q = 0; q < 32; ++q) {
            float4 v = row[q];
            c += (((int)v.x >> i) & 1) + (((int)v.y >> i) & 1) +
                 (((int)v.z >> i) & 1) + (((int)v.w >> i) & 1);
        }
        D[u] = __fmul_rn((float)c, 0.3f);
        mn = fminf(mn, D[u]);
        mx = fmaxf(mx, D[u]);
    }
    red[tid] = mn; red[256 + tid] = mx;
    __syncthreads();
    for (int w = 128; w >= 1; w >>= 1) {
        if (tid < w) {
            red[tid] = fminf(red[tid], red[tid + w]);
            red[256 + tid] = fmaxf(red[256 + tid], red[256 + tid + w]);
        }
        __syncthreads();
    }
    mn = red[0]; mx = red[256];
    float step = __fmul_rn(__fsub_rn(mx, mn), 0.03125f);
    if (step <= 0.f) step = 1.f;
#pragma unroll
    for (int u = 0; u < 4; ++u) {
        int b = tid + u * 256;
        float idx = fminf(fmaxf(floorf(__fdiv_rn(__fsub_rn(D[u], mn), step)), 0.f), 31.f);
        Dq[(i * S + s) * 1024 + b] = __fadd_rn(__fmul_rn(idx, step), mn);
    }
}

// dterm[b] = sum_{i,s} Dq[i,s,b] * (85 * 2^i)
__global__ void dterm_kernel(const float* __restrict__ Dq, float* __restrict__ dterm, int S)
{
    int b = blockIdx.x * 256 + threadIdx.x;
    if (b >= 1024) return;
    float sum = 0.f;
    for (int i = 0; i < 8; ++i) {
        float sc = (float)(85 << i);
        for (int s = 0; s < S; ++s) sum = fmaf(Dq[(i * S + s) * 1024 + b], sc, sum);
    }
    dterm[b] = sum;
}

// ---------------------------------------------------------------------------
// Layer-1 GEMM: 128x128 tile, BK=32, 8x8 acc/thread, 256 threads.
// rows = (i-i0)*1024 + b (chunk-local), cols = k*512 + f.
// A = bit_i(xqT[n][b]) extracted during staging; B = g1t[n][c].
// Accumulation order per element: a ascending 0..127 (bit-exact vs R1).
// ---------------------------------------------------------------------------
#define BK 32
__global__ __launch_bounds__(256, 4) void mm1_kernel(
    const float* __restrict__ xqT, const float* __restrict__ g1t,
    float* __restrict__ P, unsigned* __restrict__ stats, int s, int i0)
{
    __shared__ __align__(16) float As[BK][132];
    __shared__ __align__(16) float Bs[BK][132];
    __shared__ float red[512];
    const int tid = threadIdx.x;
    const int rowChunk = blockIdx.x * 128;      // [0, ni*1024)
    const int i = i0 + (rowChunk >> 10);
    const int b0 = rowChunk & 1023;
    const int colBase = blockIdx.y * 128;       // [0, 2048)
    const int nbase = s * 128;
    const int tx = tid & 15, ty = tid >> 4;

    float acc[8][8] = {};
    for (int ac = 0; ac < 4; ++ac) {
        const int n0 = nbase + ac * BK;
        __syncthreads();
#pragma unroll
        for (int u = 0; u < 4; ++u) {
            int t = u * 256 + tid;              // 0..1023
            int a = t >> 5;                     // 0..31
            int e = (t & 31) << 2;              // 0..124
            float4 av = *(const float4*)&xqT[(n0 + a) * 1024 + b0 + e];
            float4 bv = *(const float4*)&g1t[(n0 + a) * 2048 + colBase + e];
            float4 ab;
            ab.x = (float)((((int)av.x) >> i) & 1);
            ab.y = (float)((((int)av.y) >> i) & 1);
            ab.z = (float)((((int)av.z) >> i) & 1);
            ab.w = (float)((((int)av.w) >> i) & 1);
            *(float4*)&As[a][e] = ab;
            *(float4*)&Bs[a][e] = bv;
        }
        __syncthreads();
#pragma unroll 4
        for (int a = 0; a < BK; ++a) {
            float ar[8], br[8];
            *(float4*)&ar[0] = *(const float4*)&As[a][ty << 2];
            *(float4*)&ar[4] = *(const float4*)&As[a][64 + (ty << 2)];
            *(float4*)&br[0] = *(const float4*)&Bs[a][tx << 2];
            *(float4*)&br[4] = *(const float4*)&Bs[a][64 + (tx << 2)];
#pragma unroll
            for (int u = 0; u < 8; ++u)
#pragma unroll
                for (int v = 0; v < 8; ++v)
                    acc[u][v] = fmaf(ar[u], br[v], acc[u][v]);
        }
    }

    // write P: rows rowChunk + {ty*4+u, 64+ty*4+u}, cols colBase + {tx*4+v, 64+tx*4+v}
#pragma unroll
    for (int uh = 0; uh < 2; ++uh)
#pragma unroll
        for (int u = 0; u < 4; ++u) {
            int row = rowChunk + uh * 64 + (ty << 2) + u;
#pragma unroll
            for (int vh = 0; vh < 2; ++vh) {
                float4 v = make_float4(acc[uh * 4 + u][vh * 4 + 0], acc[uh * 4 + u][vh * 4 + 1],
                                       acc[uh * 4 + u][vh * 4 + 2], acc[uh * 4 + u][vh * 4 + 3]);
                *(float4*)&P[(size_t)row * 2048 + colBase + vh * 64 + (tx << 2)] = v;
            }
        }

    float mn = acc[0][0], mx = acc[0][0];
#pragma unroll
    for (int u = 0; u < 8; ++u)
#pragma unroll
        for (int v = 0; v < 8; ++v) { mn = fminf(mn, acc[u][v]); mx = fmaxf(mx, acc[u][v]); }
    red[tid] = mn; red[256 + tid] = mx;
    __syncthreads();
    for (int w = 128; w >= 1; w >>= 1) {
        if (tid < w) {
            red[tid] = fminf(red[tid], red[tid + w]);
            red[256 + tid] = fmaxf(red[256 + tid], red[256 + tid + w]);
        }
        __syncthreads();
    }
    if (tid == 0) {
        int k = colBase >> 9;
        int slot = ((s * 8 + i) * 4 + k) * 2;
        atomicMin(&stats[slot], __float_as_uint(red[0]));      // P >= 0: uint order == float order
        atomicMax(&stats[slot + 1], __float_as_uint(red[256]));
    }
}

// ADC-quantize chunk planes and accumulate sum_{i,k} Pq*scal into acc1[b][f]
__global__ void quant1_kernel(const float* __restrict__ P, const unsigned* __restrict__ stats,
                              float* __restrict__ acc1, int s, int i0, int ni)
{
    int gid = blockIdx.x * 256 + threadIdx.x;  // 524288
    int b = gid >> 9, f = gid & 511;
    float sum = 0.f;
    for (int il = 0; il < ni; ++il) {
        int i = i0 + il;
#pragma unroll
        for (int k = 0; k < 4; ++k) {
            int slot = ((s * 8 + i) * 4 + k) * 2;
            float mn = __uint_as_float(stats[slot]);
            float mx = __uint_as_float(stats[slot + 1]);
            float step = __fmul_rn(__fsub_rn(mx, mn), 0.03125f);
            if (step <= 0.f) step = 1.f;
            float val = P[(size_t)(il * 1024 + b) * 2048 + (k << 9) + f];
            float idx = fminf(fmaxf(floorf(__fdiv_rn(__fsub_rn(val, mn), step)), 0.f), 31.f);
            float pq = __fadd_rn(__fmul_rn(idx, step), mn);
            sum = fmaf(pq, (float)(1 << (i + 2 * k)), sum);
        }
    }
    acc1[gid] += sum;
}

// out1 -> tanh -> xq2 (layer-2 quantized input codes)
__global__ void finish1_kernel(const float* __restrict__ acc1, const float* __restrict__ dterm1,
                               const float* __restrict__ sx1, float* __restrict__ xq2)
{
    int gid = blockIdx.x * 256 + threadIdx.x;  // 524288
    int b = gid >> 9;
    float total = __fsub_rn(acc1[gid], dterm1[b]);
    float acc = __fdiv_rn(total, 0.9f);
    float o = __fsub_rn(__fdiv_rn(__fmul_rn(2.f, acc), 65025.f), __fdiv_rn(sx1[b], 255.f));
    float h = tanhf(o);
    h = fminf(fmaxf(h, 0.f), 1.f);
    xq2[gid] = rintf(__fmul_rn(h, 255.f));
}

__global__ void sx2_kernel(const float* __restrict__ xq2, float* __restrict__ sx2)
{
    __shared__ float red[128];
    int b = blockIdx.x;
    float psum = 0.f;
    for (int n = threadIdx.x; n < 512; n += 128) psum += xq2[b * 512 + n];
    red[threadIdx.x] = psum;
    __syncthreads();
    for (int w = 64; w >= 1; w >>= 1) {
        if (threadIdx.x < w) red[threadIdx.x] += red[threadIdx.x + w];
        __syncthreads();
    }
    if (threadIdx.x == 0) sx2[b] = red[0];
}

// Layer-2 matmul: thread per (s,b,f), 32 accumulators (i,k)
__global__ void mm2_kernel(const float* __restrict__ xq2, const float* __restrict__ g2t,
                           float* __restrict__ P2)
{
    int gid = blockIdx.x * 256 + threadIdx.x;  // 40960
    if (gid >= 40960) return;
    int f = gid % 10;
    int b = (gid / 10) & 1023;
    int s = gid / 10240;
    float acc[8][4] = {};
    for (int a = 0; a < 128; ++a) {
        int n = s * 128 + a;
        int xi = (int)xq2[b * 512 + n];
        float g0 = g2t[n * 40 + f];
        float gA = g2t[n * 40 + 10 + f];
        float gB = g2t[n * 40 + 20 + f];
        float gC = g2t[n * 40 + 30 + f];
#pragma unroll
        for (int i = 0; i < 8; ++i) {
            float bi = (float)((xi >> i) & 1);
            acc[i][0] = fmaf(bi, g0, acc[i][0]);
            acc[i][1] = fmaf(bi, gA, acc[i][1]);
            acc[i][2] = fmaf(bi, gB, acc[i][2]);
            acc[i][3] = fmaf(bi, gC, acc[i][3]);
        }
    }
#pragma unroll
    for (int i = 0; i < 8; ++i)
#pragma unroll
        for (int k = 0; k < 4; ++k)
            P2[(size_t)((s * 8 + i) * 4 + k) * 10240 + b * 10 + f] = acc[i][k];
}

__global__ void stat2_kernel(const float* __restrict__ P2, float2* __restrict__ stats2)
{
    __shared__ float red[512];
    int p = blockIdx.x;  // 128 planes
    int tid = threadIdx.x;
    float mn = FLTMAX, mx = -FLTMAX;
    for (int t = tid; t < 10240; t += 256) {
        float v = P2[(size_t)p * 10240 + t];
        mn = fminf(mn, v); mx = fmaxf(mx, v);
    }
    red[tid] = mn; red[256 + tid] = mx;
    __syncthreads();
    for (int w = 128; w >= 1; w >>= 1) {
        if (tid < w) {
            red[tid] = fminf(red[tid], red[tid + w]);
            red[256 + tid] = fmaxf(red[256 + tid], red[256 + tid + w]);
        }
        __syncthreads();
    }
    if (tid == 0) {
        float step = __fmul_rn(__fsub_rn(red[256], red[0]), 0.03125f);
        if (step <= 0.f) step = 1.f;
        stats2[p] = make_float2(red[0], step);
    }
}

__global__ void out2_kernel(const float* __restrict__ P2, const float2* __restrict__ stats2,
                            const float* __restrict__ dterm2, const float* __restrict__ sx2,
                            float* __restrict__ out)
{
    int gid = blockIdx.x * 256 + threadIdx.x;  // 10240
    if (gid >= 10240) return;
    int b = gid / 10;
    float sum = 0.f;
    for (int s = 0; s < 4; ++s)
        for (int i = 0; i < 8; ++i)
#pragma unroll
            for (int k = 0; k < 4; ++k) {
                int p = (s * 8 + i) * 4 + k;
                float2 st = stats2[p];
                float val = P2[(size_t)p * 10240 + gid];
                float idx = fminf(fmaxf(floorf(__fdiv_rn(__fsub_rn(val, st.x), st.y)), 0.f), 31.f);
                float pq = __fadd_rn(__fmul_rn(idx, st.y), st.x);
                sum = fmaf(pq, (float)(1 << (i + 2 * k)), sum);
            }
    float total = __fsub_rn(sum, dterm2[b]);
    float acc = __fdiv_rn(total, 0.9f);
    out[gid] = __fsub_rn(__fdiv_rn(__fmul_rn(2.f, acc), 65025.f), __fdiv_rn(sx2[b], 255.f));
}

extern "C" void kernel_launch(void* const* d_in, const int* in_sizes, int n_in,
                              void* d_out, int out_size, void* d_ws, size_t ws_size,
                              hipStream_t stream)
{
    const float* x      = (const float*)d_in[0];
    const float* w1     = (const float*)d_in[1];
    const float* w3     = (const float*)d_in[2];
    const float* noise1 = (const float*)d_in[3];
    const float* noise3 = (const float*)d_in[4];
    float* out = (float*)d_out;
    float* ws  = (float*)d_ws;

    // ws layout (float offsets, 16-float aligned)
    float*    xq1    = ws + 0;         // 1024*896
    float*    g1     = ws + 917504;    // 4*512*896
    float*    acc1   = ws + 2752512;   // 1024*512
    float*    xq2    = ws + 3276800;   // 1024*512
    float*    P2     = ws + 3801088;   // 128*10240
    float*    g2t    = ws + 5111808;   // 512*40
    float*    Dq1    = ws + 5132288;   // 56*1024
    float*    Dq2    = ws + 5189632;   // 32*1024
    float*    sx1    = ws + 5222400;   // 1024
    float*    sx2    = ws + 5223424;   // 1024
    float*    dterm1 = ws + 5224448;   // 1024
    float*    dterm2 = ws + 5225472;   // 1024
    float2*   stats2 = (float2*)(ws + 5226496);   // 128 pairs
    unsigned* stats1 = (unsigned*)(ws + 5226752); // 224*2
    float*    xqT    = ws + 5227200;   // 896*1024
    float*    g1t    = ws + 6144704;   // 896*2048
    float*    Ps     = ws + 7979712;   // ni * 1024 * 2048

    const size_t fixedf = 7979712;
    int ni = 8;  // i-planes per P chunk; shrink to fit ws
    while (ni > 1 && (fixedf + (size_t)ni * 2097152) * sizeof(float) > ws_size) ni >>= 1;

    init_kernel<<<2048, 256, 0, stream>>>(acc1, stats1);
    prep1_kernel<<<1024, 128, 0, stream>>>(x, xq1, sx1);
    prepg1_kernel<<<1792, 256, 0, stream>>>(w1, noise1, g1);
    transpose_kernel<<<dim3(28, 32), 256, 0, stream>>>(xq1, xqT, 1024, 896);
    transpose_kernel<<<dim3(28, 64), 256, 0, stream>>>(g1, g1t, 2048, 896);
    dq_kernel<<<56, 256, 0, stream>>>(xq1, Dq1, 7, 896);
    dterm_kernel<<<4, 256, 0, stream>>>(Dq1, dterm1, 7);

    for (int s = 0; s < 7; ++s)
        for (int i0 = 0; i0 < 8; i0 += ni) {
            mm1_kernel<<<dim3(8 * ni, 16), 256, 0, stream>>>(xqT, g1t, Ps, stats1, s, i0);
            quant1_kernel<<<2048, 256, 0, stream>>>(Ps, stats1, acc1, s, i0, ni);
        }

    finish1_kernel<<<2048, 256, 0, stream>>>(acc1, dterm1, sx1, xq2);
    sx2_kernel<<<1024, 128, 0, stream>>>(xq2, sx2);
    prepg2_kernel<<<20, 256, 0, stream>>>(w3, noise3, g2t);
    dq_kernel<<<32, 256, 0, stream>>>(xq2, Dq2, 4, 512);
    dterm_kernel<<<4, 256, 0, stream>>>(Dq2, dterm2, 4);
    mm2_kernel<<<160, 256, 0, stream>>>(xq2, g2t, P2);
    stat2_kernel<<<128, 256, 0, stream>>>(P2, stats2);
    out2_kernel<<<40, 256, 0, stream>>>(P2, stats2, dterm2, sx2, out);
}